// Round 1
// baseline (277.253 us; speedup 1.0000x reference)
//
#include <hip/hip_runtime.h>

#ifndef __has_builtin
#define __has_builtin(x) 0
#endif

__device__ __forceinline__ float fast_exp2(float x) {
#if __has_builtin(__builtin_amdgcn_exp2f)
    return __builtin_amdgcn_exp2f(x);
#else
    return exp2f(x);
#endif
}
__device__ __forceinline__ float fast_rcp(float x) {
#if __has_builtin(__builtin_amdgcn_rcpf)
    return __builtin_amdgcn_rcpf(x);
#else
    return 1.0f / x;
#endif
}

constexpr int TT = 32;   // directions T
constexpr int SS = 32;   // steps S
constexpr int BB = 64;   // graphs B
constexpr int TILE = 256;
constexpr int CPB_N = 8;   // chunks per graph, node pass  -> 512 blocks
constexpr int CPB_E = 16;  // chunks per graph, edge pass  -> 1024 blocks
constexpr float STEEP_LOG2E = 50.0f * 1.44269504088896340736f;

// ---- graph boundary detection over sorted batch -> starts[0..B] ----
__global__ void bounds_k(const int* __restrict__ batch, int N, int* __restrict__ starts) {
    int n = blockIdx.x * blockDim.x + threadIdx.x;
    if (n >= N) return;
    int g = batch[n];
    int gp = (n == 0) ? -1 : batch[n - 1];
    for (int g2 = gp + 1; g2 <= g; ++g2) starts[g2] = n;
    if (n == N - 1) {
        for (int g2 = g + 1; g2 <= BB; ++g2) starts[g2] = N;
    }
}

// ---- counting sort of edges by graph(src) ----
__global__ void hist_k(const int* __restrict__ src, const int* __restrict__ batch,
                       int E, int* __restrict__ cnt) {
    __shared__ int h[BB];
    for (int i = threadIdx.x; i < BB; i += blockDim.x) h[i] = 0;
    __syncthreads();
    for (int e = blockIdx.x * blockDim.x + threadIdx.x; e < E; e += gridDim.x * blockDim.x)
        atomicAdd(&h[batch[src[e]]], 1);
    __syncthreads();
    for (int i = threadIdx.x; i < BB; i += blockDim.x)
        if (h[i]) atomicAdd(&cnt[i], h[i]);
}

__global__ void scan_k(const int* __restrict__ cnt, int* __restrict__ offs,
                       int* __restrict__ cursor) {
    if (threadIdx.x == 0) {
        int acc = 0;
        for (int g = 0; g < BB; ++g) { offs[g] = acc; cursor[g] = acc; acc += cnt[g]; }
        offs[BB] = acc;
    }
}

__global__ void scatter_k(const int* __restrict__ src, const int* __restrict__ dst,
                          const int* __restrict__ batch, int E,
                          int* __restrict__ cursor,
                          int* __restrict__ ssrc, int* __restrict__ sdst) {
    for (int e = blockIdx.x * blockDim.x + threadIdx.x; e < E; e += gridDim.x * blockDim.x) {
        int s = src[e], d = dst[e];
        int g = batch[s];
        int pos = atomicAdd(&cursor[g], 1);
        ssrc[pos] = s;
        sdst[pos] = d;
    }
}

// ---- main ECT accumulation pass ----
// Block -> (graph g, chunk c). Thread owns t = tid&31 and 4 s-values (s = tid>>5 + 8k).
// Heights for a tile of elements staged in LDS (transposed, padded: conflict-free).
template<bool EDGE, int CPB>
__global__ __launch_bounds__(256) void ect_pass(
    const float* __restrict__ x, const float* __restrict__ v,
    const float* __restrict__ lin,
    const int* __restrict__ ssrc, const int* __restrict__ sdst,
    const int* __restrict__ starts, float* __restrict__ out, float sign)
{
    __shared__ float hbuf[TT][TILE + 1];

    const int g = blockIdx.x / CPB;
    const int c = blockIdx.x % CPB;
    const int s0 = starts[g], s1 = starts[g + 1];
    const int len = s1 - s0;
    const int chunk = (len + CPB - 1) / CPB;
    const int lo = s0 + c * chunk;
    const int hi = min(s1, lo + chunk);

    const int tid = threadIdx.x;
    const int t_out = tid & 31;
    const int s_row = tid >> 5;

    float ck[4];
#pragma unroll
    for (int k = 0; k < 4; ++k) ck[k] = STEEP_LOG2E * lin[s_row + 8 * k];
    float acc[4] = {0.f, 0.f, 0.f, 0.f};

    for (int base = lo; base < hi; base += TILE) {
        const int cnt = min(TILE, hi - base);
        __syncthreads();   // protect hbuf reuse across tiles
        if (tid < cnt) {
            const int i = base + tid;
            float a0, a1, a2, b0 = 0.f, b1 = 0.f, b2 = 0.f;
            if (EDGE) {
                const int sn = ssrc[i], dn = sdst[i];
                a0 = x[3 * sn]; a1 = x[3 * sn + 1]; a2 = x[3 * sn + 2];
                b0 = x[3 * dn]; b1 = x[3 * dn + 1]; b2 = x[3 * dn + 2];
            } else {
                a0 = x[3 * i]; a1 = x[3 * i + 1]; a2 = x[3 * i + 2];
            }
#pragma unroll
            for (int t = 0; t < TT; ++t) {
                const float v0 = v[t], v1 = v[TT + t], v2 = v[2 * TT + t];
                float h = fmaf(a0, v0, fmaf(a1, v1, a2 * v2));
                if (EDGE) {
                    const float h2 = fmaf(b0, v0, fmaf(b1, v1, b2 * v2));
                    h = fmaxf(h, h2);
                }
                hbuf[t][tid] = h;
            }
        }
        __syncthreads();
        for (int e = 0; e < cnt; ++e) {
            const float m = hbuf[t_out][e] * STEEP_LOG2E;
#pragma unroll
            for (int k = 0; k < 4; ++k) {
                const float u = fast_exp2(m - ck[k]);       // exp(-50*(lin-h))
                acc[k] += fast_rcp(1.0f + u);               // sigmoid
            }
        }
    }

#pragma unroll
    for (int k = 0; k < 4; ++k) {
        const int s = s_row + 8 * k;
        atomicAdd(&out[(g * SS + s) * TT + t_out], sign * acc[k]);
    }
}

extern "C" void kernel_launch(void* const* d_in, const int* in_sizes, int n_in,
                              void* d_out, int out_size, void* d_ws, size_t ws_size,
                              hipStream_t stream) {
    const float* x   = (const float*)d_in[0];
    const float* v   = (const float*)d_in[1];
    const float* lin = (const float*)d_in[2];
    const int* edge_index = (const int*)d_in[3];
    const int* batch = (const int*)d_in[4];

    const int N = in_sizes[0] / 3;
    const int E = in_sizes[3] / 2;
    const int* src = edge_index;       // edge_index[0][:]
    const int* dst = edge_index + E;   // edge_index[1][:]
    float* out = (float*)d_out;

    char* ws = (char*)d_ws;
    int* cnt    = (int*)ws;            // 64
    int* offs   = cnt + 64;            // 65
    int* cursor = offs + 72;           // 64
    int* starts = cursor + 64;         // 65
    int* ssrc   = (int*)(ws + 4096);
    int* sdst   = ssrc + E;

    hipMemsetAsync(out, 0, (size_t)out_size * sizeof(float), stream);
    hipMemsetAsync(cnt, 0, 64 * sizeof(int), stream);

    bounds_k<<<(N + 255) / 256, 256, 0, stream>>>(batch, N, starts);
    hist_k<<<256, 256, 0, stream>>>(src, batch, E, cnt);
    scan_k<<<1, 64, 0, stream>>>(cnt, offs, cursor);
    scatter_k<<<256, 256, 0, stream>>>(src, dst, batch, E, cursor, ssrc, sdst);

    ect_pass<false, CPB_N><<<BB * CPB_N, 256, 0, stream>>>(
        x, v, lin, nullptr, nullptr, starts, out, 1.0f);
    ect_pass<true, CPB_E><<<BB * CPB_E, 256, 0, stream>>>(
        x, v, lin, ssrc, sdst, offs, out, -1.0f);
}

// Round 2
// 68.021 us; speedup vs baseline: 4.0760x; 4.0760x over previous
//
#include <hip/hip_runtime.h>

#ifndef __has_builtin
#define __has_builtin(x) 0
#endif

__device__ __forceinline__ float fast_exp2(float x) {
#if __has_builtin(__builtin_amdgcn_exp2f)
    return __builtin_amdgcn_exp2f(x);
#else
    return exp2f(x);
#endif
}
__device__ __forceinline__ float fast_rcp(float x) {
#if __has_builtin(__builtin_amdgcn_rcpf)
    return __builtin_amdgcn_rcpf(x);
#else
    return 1.0f / x;
#endif
}

constexpr int TT = 32;   // directions T
constexpr int SS = 32;   // steps S
constexpr int BB = 64;   // graphs B
constexpr int NB = 64;   // partition blocks for edge sort
constexpr int TILE = 256;
constexpr int CPB_N = 8;   // chunks per graph, node pass  -> 512 blocks
constexpr int CPB_E = 16;  // chunks per graph, edge pass  -> 1024 blocks
constexpr float STEEP_LOG2E = 50.0f * 1.44269504088896340736f;

// ---- graph boundary detection over sorted batch -> starts[0..B] ----
__global__ void bounds_k(const int* __restrict__ batch, int N, int* __restrict__ starts) {
    int n = blockIdx.x * blockDim.x + threadIdx.x;
    if (n >= N) return;
    int g = batch[n];
    int gp = (n == 0) ? -1 : batch[n - 1];
    for (int g2 = gp + 1; g2 <= g; ++g2) starts[g2] = n;
    if (n == N - 1) {
        for (int g2 = g + 1; g2 <= BB; ++g2) starts[g2] = N;
    }
}

// ---- contention-free counting sort of edges by graph(src) ----
// Phase 1: per-block histogram of a contiguous edge range (LDS only).
__global__ __launch_bounds__(256) void hist2_k(const int* __restrict__ src,
                                               const int* __restrict__ batch,
                                               int E, int* __restrict__ hist) {
    __shared__ int h[BB];
    if (threadIdx.x < BB) h[threadIdx.x] = 0;
    __syncthreads();
    const int per = (E + gridDim.x - 1) / gridDim.x;
    const int lo = blockIdx.x * per;
    const int hi = min(E, lo + per);
    for (int e = lo + threadIdx.x; e < hi; e += blockDim.x)
        atomicAdd(&h[batch[src[e]]], 1);
    __syncthreads();
    if (threadIdx.x < BB) hist[blockIdx.x * BB + threadIdx.x] = h[threadIdx.x];
}

// Phase 2: scan hist[b][g] -> base[b][g] (graph offsets folded in) + offs[0..BB].
__global__ void scan2_k(const int* __restrict__ hist, int E,
                        int* __restrict__ base, int* __restrict__ offs) {
    __shared__ int sbase[NB][BB + 1];
    __shared__ int tot[BB];
    const int g = threadIdx.x;   // 64 threads
    int acc = 0;
    for (int b = 0; b < NB; ++b) {
        sbase[b][g] = acc;
        acc += hist[b * BB + g];
    }
    tot[g] = acc;
    __syncthreads();
    if (g == 0) {
        int run = 0;
        for (int i = 0; i < BB; ++i) {
            offs[i] = run;
            run += tot[i];
            tot[i] = offs[i];            // reuse tot[] as exclusive offsets
        }
        offs[BB] = run;
    }
    __syncthreads();
    const int o = tot[g];
    for (int b = 0; b < NB; ++b)
        base[b * BB + g] = sbase[b][g] + o;
}

// Phase 3: scatter with LDS cursors only (zero global atomics).
__global__ __launch_bounds__(256) void scatter2_k(const int* __restrict__ src,
                                                  const int* __restrict__ dst,
                                                  const int* __restrict__ batch, int E,
                                                  const int* __restrict__ base,
                                                  int* __restrict__ ssrc,
                                                  int* __restrict__ sdst) {
    __shared__ int lcur[BB];
    if (threadIdx.x < BB) lcur[threadIdx.x] = base[blockIdx.x * BB + threadIdx.x];
    __syncthreads();
    const int per = (E + gridDim.x - 1) / gridDim.x;
    const int lo = blockIdx.x * per;
    const int hi = min(E, lo + per);
    for (int e = lo + threadIdx.x; e < hi; e += blockDim.x) {
        int s = src[e], d = dst[e];
        int g = batch[s];
        int pos = atomicAdd(&lcur[g], 1);
        ssrc[pos] = s;
        sdst[pos] = d;
    }
}

// ---- main ECT accumulation pass ----
// Block -> (graph g, chunk c). Thread owns t = tid&31 and 4 s-values (s = tid>>5 + 8k).
// Heights for a tile of elements staged in LDS (transposed, padded: conflict-free).
template<bool EDGE, int CPB>
__global__ __launch_bounds__(256) void ect_pass(
    const float* __restrict__ x, const float* __restrict__ v,
    const float* __restrict__ lin,
    const int* __restrict__ ssrc, const int* __restrict__ sdst,
    const int* __restrict__ starts, float* __restrict__ out, float sign)
{
    __shared__ float hbuf[TT][TILE + 1];

    const int g = blockIdx.x / CPB;
    const int c = blockIdx.x % CPB;
    const int s0 = starts[g], s1 = starts[g + 1];
    const int len = s1 - s0;
    const int chunk = (len + CPB - 1) / CPB;
    const int lo = s0 + c * chunk;
    const int hi = min(s1, lo + chunk);

    const int tid = threadIdx.x;
    const int t_out = tid & 31;
    const int s_row = tid >> 5;

    float ck[4];
#pragma unroll
    for (int k = 0; k < 4; ++k) ck[k] = STEEP_LOG2E * lin[s_row + 8 * k];
    float acc[4] = {0.f, 0.f, 0.f, 0.f};

    for (int base = lo; base < hi; base += TILE) {
        const int cnt = min(TILE, hi - base);
        __syncthreads();   // protect hbuf reuse across tiles
        if (tid < cnt) {
            const int i = base + tid;
            float a0, a1, a2, b0 = 0.f, b1 = 0.f, b2 = 0.f;
            if (EDGE) {
                const int sn = ssrc[i], dn = sdst[i];
                a0 = x[3 * sn]; a1 = x[3 * sn + 1]; a2 = x[3 * sn + 2];
                b0 = x[3 * dn]; b1 = x[3 * dn + 1]; b2 = x[3 * dn + 2];
            } else {
                a0 = x[3 * i]; a1 = x[3 * i + 1]; a2 = x[3 * i + 2];
            }
#pragma unroll
            for (int t = 0; t < TT; ++t) {
                const float v0 = v[t], v1 = v[TT + t], v2 = v[2 * TT + t];
                float h = fmaf(a0, v0, fmaf(a1, v1, a2 * v2));
                if (EDGE) {
                    const float h2 = fmaf(b0, v0, fmaf(b1, v1, b2 * v2));
                    h = fmaxf(h, h2);
                }
                hbuf[t][tid] = h;
            }
        }
        __syncthreads();
        for (int e = 0; e < cnt; ++e) {
            const float m = hbuf[t_out][e] * STEEP_LOG2E;
#pragma unroll
            for (int k = 0; k < 4; ++k) {
                const float u = fast_exp2(m - ck[k]);       // exp(-50*(lin-h))
                acc[k] += fast_rcp(1.0f + u);               // sigmoid
            }
        }
    }

#pragma unroll
    for (int k = 0; k < 4; ++k) {
        const int s = s_row + 8 * k;
        atomicAdd(&out[(g * SS + s) * TT + t_out], sign * acc[k]);
    }
}

extern "C" void kernel_launch(void* const* d_in, const int* in_sizes, int n_in,
                              void* d_out, int out_size, void* d_ws, size_t ws_size,
                              hipStream_t stream) {
    const float* x   = (const float*)d_in[0];
    const float* v   = (const float*)d_in[1];
    const float* lin = (const float*)d_in[2];
    const int* edge_index = (const int*)d_in[3];
    const int* batch = (const int*)d_in[4];

    const int N = in_sizes[0] / 3;
    const int E = in_sizes[3] / 2;
    const int* src = edge_index;       // edge_index[0][:]
    const int* dst = edge_index + E;   // edge_index[1][:]
    float* out = (float*)d_out;

    char* ws = (char*)d_ws;
    int* starts = (int*)ws;              // 65 ints
    int* offs   = starts + 128;          // 65 ints      (ws + 512)
    int* hist   = offs + 128;            // NB*BB ints   (ws + 1024)
    int* base   = hist + NB * BB;        // NB*BB ints
    int* ssrc   = (int*)(ws + 40960);
    int* sdst   = ssrc + E;

    hipMemsetAsync(out, 0, (size_t)out_size * sizeof(float), stream);

    bounds_k<<<(N + 255) / 256, 256, 0, stream>>>(batch, N, starts);
    hist2_k<<<NB, 256, 0, stream>>>(src, batch, E, hist);
    scan2_k<<<1, BB, 0, stream>>>(hist, E, base, offs);
    scatter2_k<<<NB, 256, 0, stream>>>(src, dst, batch, E, base, ssrc, sdst);

    ect_pass<false, CPB_N><<<BB * CPB_N, 256, 0, stream>>>(
        x, v, lin, nullptr, nullptr, starts, out, 1.0f);
    ect_pass<true, CPB_E><<<BB * CPB_E, 256, 0, stream>>>(
        x, v, lin, ssrc, sdst, offs, out, -1.0f);
}